// Round 3
// baseline (5364.571 us; speedup 1.0000x reference)
//
#include <hip/hip_runtime.h>
#include <hip/hip_fp16.h>
#include <stdint.h>

typedef _Float16 f16;
typedef _Float16 f16x8 __attribute__((ext_vector_type(8)));
typedef _Float16 f16x4 __attribute__((ext_vector_type(4)));
typedef float f32x4 __attribute__((ext_vector_type(4)));

#define TSTEPS 512
#define NB 256        // persistent blocks == CUs
#define NT 512        // 8 waves

__device__ __forceinline__ float sigm(float v) { return 1.0f / (1.0f + __expf(-v)); }

// Coherent (L2-bypassing, memory-side-L3) accesses for cross-XCD exchange.
__device__ __forceinline__ void ld_coh(f16x8& d, const f16* p) {
  asm volatile("global_load_dwordx4 %0, %1, off sc0 sc1" : "=v"(d) : "v"(p));
}
__device__ __forceinline__ void ld_plain(f16x8& d, const f16* p) {
  asm volatile("global_load_dwordx4 %0, %1, off" : "=v"(d) : "v"(p));
}
__device__ __forceinline__ void st_coh_f16(f16* p, f16 v) {
  asm volatile("global_store_short %0, %1, off sc0 sc1" :: "v"(p), "v"(v) : "memory");
}
__device__ __forceinline__ void st_coh_u32(unsigned* p, unsigned v) {
  asm volatile("global_store_dword %0, %1, off sc0 sc1" :: "v"(p), "v"(v) : "memory");
}
__device__ __forceinline__ uint4 ld_coh_u4(const unsigned* p) {
  uint4 d;
  asm volatile("global_load_dwordx4 %0, %1, off sc0 sc1" : "=v"(d) : "v"(p));
  return d;
}

// Persistent wavefront-pipelined 2-layer subLSTM, weights in REGISTERS.
// Block bid: layer = bid>>7, owns hidden units [8n,8n+8), n = bid&127.
// Wave w (0..7) owns K-octant [w*256, w*256+256) and computes the full
// 32batch x 32col output partial over it (acc[2][2] of 16x16 MFMA tiles).
// Cross-wave K-reduce via padded LDS (all phases <=2-way bank aliasing = free).
// Grid sync: per-block flag array + all-wave polling (no atomics, no fences).
template<int USE_X16>
__global__ __launch_bounds__(NT, 2)
void sublstm_persistent(const float* __restrict__ x,
                        const float* __restrict__ wih0, const float* __restrict__ whh0,
                        const float* __restrict__ b0,
                        const float* __restrict__ wih1, const float* __restrict__ whh1,
                        const float* __restrict__ b1,
                        const f16* __restrict__ x16,
                        f16* __restrict__ h1buf, f16* __restrict__ h2buf,
                        unsigned* __restrict__ flags,
                        float* __restrict__ out)
{
  __shared__ float red[8][32][36];   // 36,864 B  per-wave partials (pad 36: <=2-way)
  __shared__ float gatesS[32][36];   //  4,608 B
  __shared__ float biasS[32];

  const int bid   = blockIdx.x;
  const int layer = bid >> 7;
  const int n     = bid & 127;
  const int tid   = threadIdx.x;
  const int lane  = tid & 63;
  const int w     = tid >> 6;
  const int c15   = lane & 15;
  const int g     = lane >> 4;

  const float* wih = layer ? wih1 : wih0;
  const float* whh = layer ? whh1 : whh0;
  const float* bb  = layer ? b1   : b0;

  // ---- one-time: weight slice -> registers (fp32 -> fp16) ----
  // breg[cc][ks] = B[col = cc*16 + c15][k = w*256 + ks*32 + g*8 .. +8)
  const int kbase = w * 256 + g * 8;
  f16x8 breg[2][8];
  #pragma unroll
  for (int cc = 0; cc < 2; ++cc) {
    const int col  = cc * 16 + c15;
    const int gate = ((col >> 3) << 10) + (n << 3) + (col & 7);
    const float* wr = (w < 4) ? (wih + (size_t)gate * 1024 + kbase)
                              : (whh + (size_t)gate * 1024 + (kbase - 1024));
    #pragma unroll
    for (int ks = 0; ks < 8; ++ks) {
      const float4 v0 = *(const float4*)(wr + ks * 32);
      const float4 v1 = *(const float4*)(wr + ks * 32 + 4);
      breg[cc][ks] = (f16x8){(f16)v0.x,(f16)v0.y,(f16)v0.z,(f16)v0.w,
                             (f16)v1.x,(f16)v1.y,(f16)v1.z,(f16)v1.w};
    }
  }
  if (tid < 32) biasS[tid] = bb[((tid >> 3) << 10) + (n << 3) + (tid & 7)];
  __syncthreads();

  float c = 0.0f;        // cell state: thread tid<256 owns (b=tid>>3, jj=tid&7)
  f16x8 af[2][8];

  // prime x-prefetch for layer-1 x-waves (t=0)
  if (USE_X16 && layer == 0 && w < 4) {
    #pragma unroll
    for (int m = 0; m < 2; ++m) {
      const f16* bp = x16 + (size_t)(m * 16 + c15) * 1024 + kbase;
      #pragma unroll
      for (int ks = 0; ks < 8; ++ks) ld_plain(af[m][ks], bp + ks * 32);
    }
  }

  for (int s = 0; s <= TSTEPS; ++s) {
    const int p_in  = s & 1;
    const int p_out = (s + 1) & 1;
    const bool active = (layer == 0) ? (s < TSTEPS) : (s >= 1);
    const int t = (layer == 0) ? s : (s - 1);

    if (active) {
      const f16* h1in = h1buf + (size_t)p_in * (32 * 1024);
      const f16* h2in = h2buf + (size_t)p_in * (32 * 1024);

      if (layer == 0 && w < 4) {
        if (!USE_X16) {
          #pragma unroll
          for (int m = 0; m < 2; ++m) {
            const float* bp = x + ((size_t)t * 32 + m * 16 + c15) * 1024 + kbase;
            #pragma unroll
            for (int ks = 0; ks < 8; ++ks) {
              const float4 v0 = *(const float4*)(bp + ks * 32);
              const float4 v1 = *(const float4*)(bp + ks * 32 + 4);
              af[m][ks] = (f16x8){(f16)v0.x,(f16)v0.y,(f16)v0.z,(f16)v0.w,
                                  (f16)v1.x,(f16)v1.y,(f16)v1.z,(f16)v1.w};
            }
          }
        } // else: af prefetched under previous barrier
      } else {
        const f16* src; int koff;
        if (layer == 0)   { src = h1in; koff = kbase - 1024; }
        else if (w < 4)   { src = h1in; koff = kbase; }
        else              { src = h2in; koff = kbase - 1024; }
        #pragma unroll
        for (int m = 0; m < 2; ++m) {
          const f16* bp = src + (size_t)(m * 16 + c15) * 1024 + koff;
          #pragma unroll
          for (int ks = 0; ks < 8; ++ks) ld_coh(af[m][ks], bp + ks * 32);
        }
      }
      asm volatile("s_waitcnt vmcnt(0)" ::: "memory");
      __builtin_amdgcn_sched_barrier(0);

      f32x4 acc[2][2] = {{{0,0,0,0},{0,0,0,0}},{{0,0,0,0},{0,0,0,0}}};
      #pragma unroll
      for (int ks = 0; ks < 8; ++ks)
        #pragma unroll
        for (int m = 0; m < 2; ++m)
          #pragma unroll
          for (int cc = 0; cc < 2; ++cc)
            acc[m][cc] = __builtin_amdgcn_mfma_f32_16x16x32_f16(af[m][ks], breg[cc][ks], acc[m][cc], 0, 0, 0);

      // C frag: row = m*16 + g*4 + r, col = cc*16 + c15
      #pragma unroll
      for (int m = 0; m < 2; ++m)
        #pragma unroll
        for (int cc = 0; cc < 2; ++cc)
          #pragma unroll
          for (int r = 0; r < 4; ++r)
            red[w][m * 16 + g * 4 + r][cc * 16 + c15] = acc[m][cc][r];
    }
    __syncthreads();

    if (active) {
      #pragma unroll
      for (int rep = 0; rep < 2; ++rep) {
        const int idx = tid + rep * 512;
        const int b = idx >> 5, col = idx & 31;
        float tot = biasS[col];
        #pragma unroll
        for (int ww = 0; ww < 8; ++ww) tot += red[ww][b][col];
        gatesS[b][col] = sigm(tot);
      }
    }
    __syncthreads();

    if (active && tid < 256) {
      const int b = tid >> 3, jj = tid & 7;
      const float ig = gatesS[b][jj];
      const float og = gatesS[b][8 + jj];
      const float zg = gatesS[b][16 + jj];
      const float fg = gatesS[b][24 + jj];
      c = c * fg + zg - ig;
      const float h = sigm(c) - og;
      const int j = (n << 3) + jj;
      f16* hb = ((layer == 0) ? h1buf : h2buf) + (size_t)p_out * (32 * 1024);
      st_coh_f16(hb + b * 1024 + j, (f16)h);
      if (layer == 1) out[((size_t)t * 32 + b) * 1024 + j] = h;
    }

    // next-step x prefetch stays in flight across the barrier; counted vmcnt
    // drains only the (older) h/out stores.
    if (USE_X16 && layer == 0 && tid < 256 && (s + 1) < TSTEPS) {
      #pragma unroll
      for (int m = 0; m < 2; ++m) {
        const f16* bp = x16 + ((size_t)(s + 1) * 32 + m * 16 + c15) * 1024 + kbase;
        #pragma unroll
        for (int ks = 0; ks < 8; ++ks) ld_plain(af[m][ks], bp + ks * 32);
      }
      asm volatile("s_waitcnt vmcnt(16)" ::: "memory");
    } else {
      asm volatile("s_waitcnt vmcnt(0)" ::: "memory");
    }
    __syncthreads();   // all stores drained block-wide

    if (tid == 0) st_coh_u32(flags + bid, (unsigned)(s + 1));

    { // all-wave flag poll: lane l watches flags[4l..4l+4)
      const unsigned target = (unsigned)(s + 1);
      const unsigned* fp = flags + lane * 4;
      while (true) {
        uint4 d = ld_coh_u4(fp);
        asm volatile("s_waitcnt vmcnt(0)" ::: "memory");
        if (__all(d.x >= target && d.y >= target && d.z >= target && d.w >= target)) break;
        __builtin_amdgcn_s_sleep(1);
      }
    }
  }
}

__global__ void cvt_x_kernel(const float4* __restrict__ in, f16x4* __restrict__ outv, int n4) {
  int i = blockIdx.x * blockDim.x + threadIdx.x;
  const int stride = gridDim.x * blockDim.x;
  for (; i < n4; i += stride) {
    const float4 v = in[i];
    outv[i] = (f16x4){(f16)v.x, (f16)v.y, (f16)v.z, (f16)v.w};
  }
}

extern "C" void kernel_launch(void* const* d_in, const int* in_sizes, int n_in,
                              void* d_out, int out_size, void* d_ws, size_t ws_size,
                              hipStream_t stream) {
  const float* x    = (const float*)d_in[0];
  const float* wih0 = (const float*)d_in[1];
  const float* whh0 = (const float*)d_in[2];
  const float* b0   = (const float*)d_in[3];
  const float* wih1 = (const float*)d_in[4];
  const float* whh1 = (const float*)d_in[5];
  const float* b1   = (const float*)d_in[6];
  float* out = (float*)d_out;

  const size_t X16B   = (size_t)512 * 32 * 1024 * 2;  // fp16 copy of x
  const size_t HBUFB  = 2 * 32 * 1024 * 2;            // double-buffered h (fp16)
  const size_t STATEB = 2 * HBUFB + 4096;             // h1 + h2 + flags

  char* ws = (char*)d_ws;
  const bool use_x16 = ws_size >= X16B + STATEB;
  const size_t soff = use_x16 ? X16B : 0;
  f16* x16        = (f16*)ws;
  f16* h1buf      = (f16*)(ws + soff);
  f16* h2buf      = (f16*)(ws + soff + HBUFB);
  unsigned* flags = (unsigned*)(ws + soff + 2 * HBUFB);

  hipMemsetAsync(ws + soff, 0, STATEB, stream);

  if (use_x16) {
    const int n4 = 512 * 32 * 1024 / 4;
    cvt_x_kernel<<<2048, 256, 0, stream>>>((const float4*)x, (f16x4*)x16, n4);
    sublstm_persistent<1><<<NB, NT, 0, stream>>>(x, wih0, whh0, b0, wih1, whh1, b1,
                                                 x16, h1buf, h2buf, flags, out);
  } else {
    sublstm_persistent<0><<<NB, NT, 0, stream>>>(x, wih0, whh0, b0, wih1, whh1, b1,
                                                 x16, h1buf, h2buf, flags, out);
  }
}

// Round 7
// 4466.789 us; speedup vs baseline: 1.2010x; 1.2010x over previous
//
#include <hip/hip_runtime.h>
#include <hip/hip_fp16.h>
#include <stdint.h>

typedef _Float16 f16;
typedef _Float16 f16x8 __attribute__((ext_vector_type(8)));
typedef _Float16 f16x4 __attribute__((ext_vector_type(4)));
typedef float f32x4 __attribute__((ext_vector_type(4)));

#define TSTEPS 512
#define NB 256        // persistent blocks == CUs
#define NT 512        // 8 waves
#define HN (32 * 1024)

__device__ __forceinline__ float sigm(float v) { return 1.0f / (1.0f + __expf(-v)); }

// Coherent (L2-bypassing, memory-side-L3) accesses for cross-XCD exchange.
__device__ __forceinline__ void ld_coh(f16x8& d, const f16* p) {
  asm volatile("global_load_dwordx4 %0, %1, off sc0 sc1" : "=v"(d) : "v"(p));
}
__device__ __forceinline__ void ld_plain(f16x8& d, const f16* p) {
  asm volatile("global_load_dwordx4 %0, %1, off" : "=v"(d) : "v"(p));
}
__device__ __forceinline__ void st_coh_f16(f16* p, f16 v) {
  asm volatile("global_store_short %0, %1, off sc0 sc1" :: "v"(p), "v"(v) : "memory");
}

// R2's PROVEN barrier, verbatim: monotonic count (no reset race). Entry does a
// full vmcnt(0) drain of this wave's sc1 h-stores before counting, so a
// spinner observing gen==target also observes all h data at the coherence
// point (empirically validated green in R2 across many launches).
__device__ __forceinline__ void grid_barrier(unsigned* cnt, unsigned* gen, unsigned& myGen) {
  asm volatile("s_waitcnt vmcnt(0)" ::: "memory");  // drain asm sc1 stores (all threads)
  __syncthreads();
  if (threadIdx.x == 0) {
    const unsigned target = myGen + 1u;
    const unsigned a = __hip_atomic_fetch_add(cnt, 1u, __ATOMIC_RELAXED, __HIP_MEMORY_SCOPE_AGENT);
    if (a == (unsigned)NB * target - 1u) {
      __hip_atomic_store(gen, target, __ATOMIC_RELAXED, __HIP_MEMORY_SCOPE_AGENT);
    } else {
      while (__hip_atomic_load(gen, __ATOMIC_RELAXED, __HIP_MEMORY_SCOPE_AGENT) < target) {
        __builtin_amdgcn_s_sleep(2);
      }
    }
    myGen = target;
  }
  __syncthreads();
}

// Persistent wavefront-pipelined 2-layer subLSTM, weights in registers (R3 core).
// Block bid: layer = bid>>7, owns hidden units [8n,8n+8), n = bid&127.
// Wave w owns K-octant [w*256,+256) of the fused [x|h1] (L1) / [h1|h2] (L2) input.
// Interval s: layer-1 computes t=s, layer-2 computes t=s-1. One R2-barrier per
// interval provides both the data-ready and WAR ordering for the double buffers.
template<int USE_X16>
__global__ __launch_bounds__(NT, 2)
void sublstm_persistent(const float* __restrict__ x,
                        const float* __restrict__ wih0, const float* __restrict__ whh0,
                        const float* __restrict__ b0,
                        const float* __restrict__ wih1, const float* __restrict__ whh1,
                        const float* __restrict__ b1,
                        const f16* __restrict__ x16,
                        f16* __restrict__ h1buf, f16* __restrict__ h2buf,
                        unsigned* __restrict__ bar,
                        float* __restrict__ out)
{
  __shared__ float red[8][32][36];   // per-wave partials (pad 36: <=2-way = free)
  __shared__ float gatesS[32][36];
  __shared__ float biasS[32];

  const int bid   = blockIdx.x;
  const int layer = bid >> 7;
  const int n     = bid & 127;
  const int tid   = threadIdx.x;
  const int lane  = tid & 63;
  const int w     = tid >> 6;
  const int c15   = lane & 15;
  const int g     = lane >> 4;

  const float* wih = layer ? wih1 : wih0;
  const float* whh = layer ? whh1 : whh0;
  const float* bb  = layer ? b1   : b0;

  // ---- one-time: weight slice -> registers (fp32 -> fp16) ----
  const int kbase = w * 256 + g * 8;
  f16x8 breg[2][8];
  #pragma unroll
  for (int cc = 0; cc < 2; ++cc) {
    const int col  = cc * 16 + c15;
    const int gate = ((col >> 3) << 10) + (n << 3) + (col & 7);
    const float* wr = (w < 4) ? (wih + (size_t)gate * 1024 + kbase)
                              : (whh + (size_t)gate * 1024 + (kbase - 1024));
    #pragma unroll
    for (int ks = 0; ks < 8; ++ks) {
      const float4 v0 = *(const float4*)(wr + ks * 32);
      const float4 v1 = *(const float4*)(wr + ks * 32 + 4);
      breg[cc][ks] = (f16x8){(f16)v0.x,(f16)v0.y,(f16)v0.z,(f16)v0.w,
                             (f16)v1.x,(f16)v1.y,(f16)v1.z,(f16)v1.w};
    }
  }
  if (tid < 32) biasS[tid] = bb[((tid >> 3) << 10) + (n << 3) + (tid & 7)];
  __syncthreads();

  float c = 0.0f;        // cell state: thread tid<256 owns (b=tid>>3, jj=tid&7)
  unsigned myGen = 0;
  f16x8 af[2][8];

  for (int s = 0; s <= TSTEPS; ++s) {
    const int p_in  = s & 1;
    const int p_out = (s + 1) & 1;
    const bool active = (layer == 0) ? (s < TSTEPS) : (s >= 1);
    const int t = (layer == 0) ? s : (s - 1);

    if (active) {
      const f16* h1in = h1buf + (size_t)p_in * HN;
      const f16* h2in = h2buf + (size_t)p_in * HN;

      if (layer == 0 && w < 4) {
        // x-wave: load this step's x slice (L3-resident after first pass)
        if (USE_X16) {
          const f16* bp0 = x16 + ((size_t)t * 32 + c15) * 1024 + kbase;
          const f16* bp1 = x16 + ((size_t)t * 32 + 16 + c15) * 1024 + kbase;
          #pragma unroll
          for (int ks = 0; ks < 8; ++ks) {
            ld_plain(af[0][ks], bp0 + ks * 32);
            ld_plain(af[1][ks], bp1 + ks * 32);
          }
        } else {
          #pragma unroll
          for (int m = 0; m < 2; ++m) {
            const float* bp = x + ((size_t)t * 32 + m * 16 + c15) * 1024 + kbase;
            #pragma unroll
            for (int ks = 0; ks < 8; ++ks) {
              const float4 v0 = *(const float4*)(bp + ks * 32);
              const float4 v1 = *(const float4*)(bp + ks * 32 + 4);
              af[m][ks] = (f16x8){(f16)v0.x,(f16)v0.y,(f16)v0.z,(f16)v0.w,
                                  (f16)v1.x,(f16)v1.y,(f16)v1.z,(f16)v1.w};
            }
          }
        }
      } else {
        // h-wave: load this wave's h slice (coherent; barrier already ordered it)
        const f16* src; int koff;
        if (layer == 0)   { src = h1in; koff = kbase - 1024; }
        else if (w < 4)   { src = h1in; koff = kbase; }
        else              { src = h2in; koff = kbase - 1024; }
        #pragma unroll
        for (int m = 0; m < 2; ++m) {
          const f16* bp = src + (size_t)(m * 16 + c15) * 1024 + koff;
          #pragma unroll
          for (int ks = 0; ks < 8; ++ks) ld_coh(af[m][ks], bp + ks * 32);
        }
      }
      asm volatile("s_waitcnt vmcnt(0)" ::: "memory");
      __builtin_amdgcn_sched_barrier(0);

      f32x4 acc[2][2] = {{{0,0,0,0},{0,0,0,0}},{{0,0,0,0},{0,0,0,0}}};
      #pragma unroll
      for (int ks = 0; ks < 8; ++ks)
        #pragma unroll
        for (int m = 0; m < 2; ++m)
          #pragma unroll
          for (int cc = 0; cc < 2; ++cc)
            acc[m][cc] = __builtin_amdgcn_mfma_f32_16x16x32_f16(af[m][ks], breg[cc][ks], acc[m][cc], 0, 0, 0);

      // C frag: row = m*16 + g*4 + r, col = cc*16 + c15
      #pragma unroll
      for (int m = 0; m < 2; ++m)
        #pragma unroll
        for (int cc = 0; cc < 2; ++cc)
          #pragma unroll
          for (int r = 0; r < 4; ++r)
            red[w][m * 16 + g * 4 + r][cc * 16 + c15] = acc[m][cc][r];
    }
    __syncthreads();

    if (active) {
      #pragma unroll
      for (int rep = 0; rep < 2; ++rep) {
        const int idx = tid + rep * 512;
        const int b = idx >> 5, col = idx & 31;
        float tot = biasS[col];
        #pragma unroll
        for (int ww = 0; ww < 8; ++ww) tot += red[ww][b][col];
        gatesS[b][col] = sigm(tot);
      }
    }
    __syncthreads();

    if (active && tid < 256) {
      const int b = tid >> 3, jj = tid & 7;
      const float ig = gatesS[b][jj];
      const float og = gatesS[b][8 + jj];
      const float zg = gatesS[b][16 + jj];
      const float fg = gatesS[b][24 + jj];
      c = c * fg + zg - ig;
      const float h = sigm(c) - og;
      const int j = (n << 3) + jj;
      f16* hb = ((layer == 0) ? h1buf : h2buf) + (size_t)p_out * HN;
      st_coh_f16(hb + b * 1024 + j, (f16)h);
      if (layer == 1) out[((size_t)t * 32 + b) * 1024 + j] = h;
    }

    grid_barrier(bar, bar + 32, myGen);
  }
}

__global__ void cvt_x_kernel(const float4* __restrict__ in, f16x4* __restrict__ outv, int n4) {
  int i = blockIdx.x * blockDim.x + threadIdx.x;
  const int stride = gridDim.x * blockDim.x;
  for (; i < n4; i += stride) {
    const float4 v = in[i];
    outv[i] = (f16x4){(f16)v.x, (f16)v.y, (f16)v.z, (f16)v.w};
  }
}

extern "C" void kernel_launch(void* const* d_in, const int* in_sizes, int n_in,
                              void* d_out, int out_size, void* d_ws, size_t ws_size,
                              hipStream_t stream) {
  const float* x    = (const float*)d_in[0];
  const float* wih0 = (const float*)d_in[1];
  const float* whh0 = (const float*)d_in[2];
  const float* b0   = (const float*)d_in[3];
  const float* wih1 = (const float*)d_in[4];
  const float* whh1 = (const float*)d_in[5];
  const float* b1   = (const float*)d_in[6];
  float* out = (float*)d_out;

  const size_t X16B   = (size_t)512 * 32 * 1024 * 2;  // fp16 copy of x
  const size_t HBUFB  = (size_t)2 * HN * 2;           // double-buffered h (fp16)
  const size_t STATEB = 2 * HBUFB + 4096;             // h1 + h2 + barrier counters

  char* ws = (char*)d_ws;
  const bool use_x16 = ws_size >= X16B + STATEB;
  const size_t soff = use_x16 ? X16B : 0;
  f16* x16        = (f16*)ws;
  f16* h1buf      = (f16*)(ws + soff);
  f16* h2buf      = (f16*)(ws + soff + HBUFB);
  unsigned* bar   = (unsigned*)(ws + soff + 2 * HBUFB);

  // zero h state + barrier counters (ws is poisoned, and graph replays reuse it)
  hipMemsetAsync(ws + soff, 0, STATEB, stream);

  if (use_x16) {
    const int n4 = 512 * 32 * 1024 / 4;
    cvt_x_kernel<<<2048, 256, 0, stream>>>((const float4*)x, (f16x4*)x16, n4);
    sublstm_persistent<1><<<NB, NT, 0, stream>>>(x, wih0, whh0, b0, wih1, whh1, b1,
                                                 x16, h1buf, h2buf, bar, out);
  } else {
    sublstm_persistent<0><<<NB, NT, 0, stream>>>(x, wih0, whh0, b0, wih1, whh1, b1,
                                                 x16, h1buf, h2buf, bar, out);
  }
}

// Round 8
// 3330.576 us; speedup vs baseline: 1.6107x; 1.3411x over previous
//
#include <hip/hip_runtime.h>
#include <hip/hip_fp16.h>
#include <stdint.h>

typedef _Float16 f16;
typedef _Float16 f16x8 __attribute__((ext_vector_type(8)));
typedef _Float16 f16x4 __attribute__((ext_vector_type(4)));
typedef float f32x4 __attribute__((ext_vector_type(4)));

#define TSTEPS 512
#define NB 256        // persistent blocks == CUs
#define NT 512        // 8 waves
#define HN (32 * 1024)

__device__ __forceinline__ float sigm(float v) { return 1.0f / (1.0f + __expf(-v)); }

// Coherent (L2-bypassing, memory-side-L3) accesses for cross-XCD exchange.
__device__ __forceinline__ void ld_coh(f16x8& d, const f16* p) {
  asm volatile("global_load_dwordx4 %0, %1, off sc0 sc1" : "=v"(d) : "v"(p));
}
__device__ __forceinline__ void ld_plain(f16x8& d, const f16* p) {
  asm volatile("global_load_dwordx4 %0, %1, off" : "=v"(d) : "v"(p));
}
__device__ __forceinline__ void st_coh_f16(f16* p, f16 v) {
  asm volatile("global_store_short %0, %1, off sc0 sc1" :: "v"(p), "v"(v) : "memory");
}
__device__ __forceinline__ void st_coh_u32(unsigned* p, unsigned v) {
  asm volatile("global_store_dword %0, %1, off sc0 sc1" :: "v"(p), "v"(v) : "memory");
}
__device__ __forceinline__ uint4 ld_coh_u4(const unsigned* p) {
  uint4 d;
  asm volatile("global_load_dwordx4 %0, %1, off sc0 sc1" : "=v"(d) : "v"(p));
  return d;
}
__device__ __forceinline__ unsigned ld_coh_u32(const unsigned* p) {
  unsigned d;
  asm volatile("global_load_dword %0, %1, off sc0 sc1" : "=v"(d) : "v"(p));
  return d;
}

// Persistent wavefront-pipelined 2-layer subLSTM, weights in registers (R7 core,
// green). Barrier v2: per-block flag STORES (parallel, distinct addresses) ->
// block-0 wave-0 scans all 256 -> single gen release dword polled by lane 0 of
// every other block. Same centralized-release semantics as the green R2/R3/R7
// barriers (single release point, everyone waits for it) — only the fan-in
// mechanism changes (no serialized same-address RMW). Every poll applies rule
// #18 (vmcnt + sched_barrier before the register-only compare).
template<int USE_X16>
__global__ __launch_bounds__(NT, 2)
void sublstm_persistent(const float* __restrict__ x,
                        const float* __restrict__ wih0, const float* __restrict__ whh0,
                        const float* __restrict__ b0,
                        const float* __restrict__ wih1, const float* __restrict__ whh1,
                        const float* __restrict__ b1,
                        const f16* __restrict__ x16,
                        f16* __restrict__ h1buf, f16* __restrict__ h2buf,
                        unsigned* __restrict__ bar,   // [0..255] flags, [320] gen
                        float* __restrict__ out)
{
  __shared__ float red[8][32][36];   // per-wave partials (pad 36: <=2-way = free)
  __shared__ float gatesS[32][36];
  __shared__ float biasS[32];

  const int bid   = blockIdx.x;
  const int layer = bid >> 7;
  const int n     = bid & 127;
  const int tid   = threadIdx.x;
  const int lane  = tid & 63;
  const int w     = tid >> 6;
  const int c15   = lane & 15;
  const int g     = lane >> 4;
  unsigned* genp  = bar + 320;

  const float* wih = layer ? wih1 : wih0;
  const float* whh = layer ? whh1 : whh0;
  const float* bb  = layer ? b1   : b0;

  // ---- one-time: weight slice -> registers (fp32 -> fp16) ----
  const int kbase = w * 256 + g * 8;
  f16x8 breg[2][8];
  #pragma unroll
  for (int cc = 0; cc < 2; ++cc) {
    const int col  = cc * 16 + c15;
    const int gate = ((col >> 3) << 10) + (n << 3) + (col & 7);
    const float* wr = (w < 4) ? (wih + (size_t)gate * 1024 + kbase)
                              : (whh + (size_t)gate * 1024 + (kbase - 1024));
    #pragma unroll
    for (int ks = 0; ks < 8; ++ks) {
      const float4 v0 = *(const float4*)(wr + ks * 32);
      const float4 v1 = *(const float4*)(wr + ks * 32 + 4);
      breg[cc][ks] = (f16x8){(f16)v0.x,(f16)v0.y,(f16)v0.z,(f16)v0.w,
                             (f16)v1.x,(f16)v1.y,(f16)v1.z,(f16)v1.w};
    }
  }
  if (tid < 32) biasS[tid] = bb[((tid >> 3) << 10) + (n << 3) + (tid & 7)];
  __syncthreads();

  float c = 0.0f;        // cell state: thread tid<256 owns (b=tid>>3, jj=tid&7)
  f16x8 af[2][8];

  // prime x-prefetch for layer-0 x-waves (t=0)
  if (USE_X16 && layer == 0 && w < 4) {
    #pragma unroll
    for (int m = 0; m < 2; ++m) {
      const f16* bp = x16 + (size_t)(m * 16 + c15) * 1024 + kbase;
      #pragma unroll
      for (int ks = 0; ks < 8; ++ks) ld_plain(af[m][ks], bp + ks * 32);
    }
  }

  for (int s = 0; s <= TSTEPS; ++s) {
    const int p_in  = s & 1;
    const int p_out = (s + 1) & 1;
    const bool active = (layer == 0) ? (s < TSTEPS) : (s >= 1);
    const int t = (layer == 0) ? s : (s - 1);

    if (active) {
      const f16* h1in = h1buf + (size_t)p_in * HN;
      const f16* h2in = h2buf + (size_t)p_in * HN;

      if (layer == 0 && w < 4) {
        // x-wave: data already prefetched (USE_X16) or fp32 fallback load
        if (!USE_X16) {
          #pragma unroll
          for (int m = 0; m < 2; ++m) {
            const float* bp = x + ((size_t)t * 32 + m * 16 + c15) * 1024 + kbase;
            #pragma unroll
            for (int ks = 0; ks < 8; ++ks) {
              const float4 v0 = *(const float4*)(bp + ks * 32);
              const float4 v1 = *(const float4*)(bp + ks * 32 + 4);
              af[m][ks] = (f16x8){(f16)v0.x,(f16)v0.y,(f16)v0.z,(f16)v0.w,
                                  (f16)v1.x,(f16)v1.y,(f16)v1.z,(f16)v1.w};
            }
          }
        }
      } else {
        // h-wave: load this wave's h slice (coherent; barrier already ordered it)
        const f16* src; int koff;
        if (layer == 0)   { src = h1in; koff = kbase - 1024; }
        else if (w < 4)   { src = h1in; koff = kbase; }
        else              { src = h2in; koff = kbase - 1024; }
        #pragma unroll
        for (int m = 0; m < 2; ++m) {
          const f16* bp = src + (size_t)(m * 16 + c15) * 1024 + koff;
          #pragma unroll
          for (int ks = 0; ks < 8; ++ks) ld_coh(af[m][ks], bp + ks * 32);
        }
      }
      asm volatile("s_waitcnt vmcnt(0)" ::: "memory");
      __builtin_amdgcn_sched_barrier(0);

      f32x4 acc[2][2] = {{{0,0,0,0},{0,0,0,0}},{{0,0,0,0},{0,0,0,0}}};
      #pragma unroll
      for (int ks = 0; ks < 8; ++ks)
        #pragma unroll
        for (int m = 0; m < 2; ++m)
          #pragma unroll
          for (int cc = 0; cc < 2; ++cc)
            acc[m][cc] = __builtin_amdgcn_mfma_f32_16x16x32_f16(af[m][ks], breg[cc][ks], acc[m][cc], 0, 0, 0);

      // C frag: row = m*16 + g*4 + r, col = cc*16 + c15
      #pragma unroll
      for (int m = 0; m < 2; ++m)
        #pragma unroll
        for (int cc = 0; cc < 2; ++cc)
          #pragma unroll
          for (int r = 0; r < 4; ++r)
            red[w][m * 16 + g * 4 + r][cc * 16 + c15] = acc[m][cc][r];
    }
    __syncthreads();

    if (active) {
      #pragma unroll
      for (int rep = 0; rep < 2; ++rep) {
        const int idx = tid + rep * 512;
        const int b = idx >> 5, col = idx & 31;
        float tot = biasS[col];
        #pragma unroll
        for (int ww = 0; ww < 8; ++ww) tot += red[ww][b][col];
        gatesS[b][col] = sigm(tot);
      }
    }
    __syncthreads();

    if (active && tid < 256) {
      const int b = tid >> 3, jj = tid & 7;
      const float ig = gatesS[b][jj];
      const float og = gatesS[b][8 + jj];
      const float zg = gatesS[b][16 + jj];
      const float fg = gatesS[b][24 + jj];
      c = c * fg + zg - ig;
      const float h = sigm(c) - og;
      const int j = (n << 3) + jj;
      f16* hb = ((layer == 0) ? h1buf : h2buf) + (size_t)p_out * HN;
      st_coh_f16(hb + b * 1024 + j, (f16)h);
      if (layer == 1) out[((size_t)t * 32 + b) * 1024 + j] = h;
    }

    if (s == TSTEPS) break;   // no successor -> no barrier needed

    // ---- barrier v2 ----
    asm volatile("s_waitcnt vmcnt(0)" ::: "memory");   // drain this wave's stores
    __syncthreads();                                   // all waves' stores drained
    {
      const unsigned target = (unsigned)(s + 1);
      if (w == 0) {
        if (bid == 0) {
          if (lane == 0) st_coh_u32(bar + 0, target);
          const unsigned* p = bar + (lane << 2);
          while (true) {
            uint4 d = ld_coh_u4(p);
            asm volatile("s_waitcnt vmcnt(0)" ::: "memory");
            __builtin_amdgcn_sched_barrier(0);
            if (__all(d.x >= target && d.y >= target && d.z >= target && d.w >= target)) break;
            __builtin_amdgcn_s_sleep(1);
          }
          if (lane == 0) st_coh_u32(genp, target);
        } else if (lane == 0) {
          st_coh_u32(bar + bid, target);
          while (true) {
            const unsigned gv = ld_coh_u32(genp);
            asm volatile("s_waitcnt vmcnt(0)" ::: "memory");
            __builtin_amdgcn_sched_barrier(0);
            if (gv >= target) break;
            __builtin_amdgcn_s_sleep(2);
          }
        }
      }
      // x-prefetch for next step overlaps the gen wait (plain loads, not
      // drained by the final syncthreads; awaited by the pre-MFMA vmcnt(0)).
      if (USE_X16 && layer == 0 && w < 4 && (s + 1) < TSTEPS) {
        #pragma unroll
        for (int m = 0; m < 2; ++m) {
          const f16* bp = x16 + ((size_t)(s + 1) * 32 + m * 16 + c15) * 1024 + kbase;
          #pragma unroll
          for (int ks = 0; ks < 8; ++ks) ld_plain(af[m][ks], bp + ks * 32);
        }
      }
      __syncthreads();   // release: wave 0 observed gen
    }
  }
}

__global__ void cvt_x_kernel(const float4* __restrict__ in, f16x4* __restrict__ outv, int n4) {
  int i = blockIdx.x * blockDim.x + threadIdx.x;
  const int stride = gridDim.x * blockDim.x;
  for (; i < n4; i += stride) {
    const float4 v = in[i];
    outv[i] = (f16x4){(f16)v.x, (f16)v.y, (f16)v.z, (f16)v.w};
  }
}

extern "C" void kernel_launch(void* const* d_in, const int* in_sizes, int n_in,
                              void* d_out, int out_size, void* d_ws, size_t ws_size,
                              hipStream_t stream) {
  const float* x    = (const float*)d_in[0];
  const float* wih0 = (const float*)d_in[1];
  const float* whh0 = (const float*)d_in[2];
  const float* b0   = (const float*)d_in[3];
  const float* wih1 = (const float*)d_in[4];
  const float* whh1 = (const float*)d_in[5];
  const float* b1   = (const float*)d_in[6];
  float* out = (float*)d_out;

  const size_t X16B   = (size_t)512 * 32 * 1024 * 2;  // fp16 copy of x
  const size_t HBUFB  = (size_t)2 * HN * 2;           // double-buffered h (fp16)
  const size_t STATEB = 2 * HBUFB + 4096;             // h1 + h2 + flags/gen

  char* ws = (char*)d_ws;
  const bool use_x16 = ws_size >= X16B + STATEB;
  const size_t soff = use_x16 ? X16B : 0;
  f16* x16        = (f16*)ws;
  f16* h1buf      = (f16*)(ws + soff);
  f16* h2buf      = (f16*)(ws + soff + HBUFB);
  unsigned* bar   = (unsigned*)(ws + soff + 2 * HBUFB);

  // zero h state + flags/gen (ws is poisoned, and graph replays reuse it)
  hipMemsetAsync(ws + soff, 0, STATEB, stream);

  if (use_x16) {
    const int n4 = 512 * 32 * 1024 / 4;
    cvt_x_kernel<<<2048, 256, 0, stream>>>((const float4*)x, (f16x4*)x16, n4);
    sublstm_persistent<1><<<NB, NT, 0, stream>>>(x, wih0, whh0, b0, wih1, whh1, b1,
                                                 x16, h1buf, h2buf, bar, out);
  } else {
    sublstm_persistent<0><<<NB, NT, 0, stream>>>(x, wih0, whh0, b0, wih1, whh1, b1,
                                                 x16, h1buf, h2buf, bar, out);
  }
}